// Round 3
// baseline (2821.685 us; speedup 1.0000x reference)
//
#include <hip/hip_runtime.h>
#include <hip/hip_bf16.h>
#include <math.h>

#define N_TOK 8192
#define DIM   1024
#define NEXP  64
#define TOPK  8

typedef __attribute__((ext_vector_type(8))) short short8;
typedef __attribute__((ext_vector_type(4))) float floatx4;

static __device__ __forceinline__ short f2bf(float f) {
    union { float f; unsigned u; } c; c.f = f;
    unsigned r = c.u + 0x7FFF + ((c.u >> 16) & 1);   // RNE
    return (short)(r >> 16);
}

// ---------------- router logits (fp32 GEMM, 32 tokens x 64 experts per block) ----------------
__global__ void k_router(const float* __restrict__ h, const float* __restrict__ gw,
                         float* __restrict__ logits) {
    __shared__ float hs[32 * 68];
    __shared__ float gs[64 * 68];
    int tid = threadIdx.x;
    int t0 = blockIdx.x * 32;
    int tm = tid & 15;    // tokens {tm, tm+16}
    int en = tid >> 4;    // experts {en, en+16, en+32, en+48}
    float acc[2][4] = {{0.f,0.f,0.f,0.f},{0.f,0.f,0.f,0.f}};

    for (int k0 = 0; k0 < DIM; k0 += 64) {
        {   // stage h tile 32x64
            int row = tid >> 3, seg = (tid & 7) * 8;
            const float* src = h + (size_t)(t0 + row) * DIM + k0 + seg;
            *(float4*)&hs[row*68 + seg]     = *(const float4*)src;
            *(float4*)&hs[row*68 + seg + 4] = *(const float4*)(src + 4);
        }
        {   // stage gw tile 64x64
            int row = tid >> 2, seg = (tid & 3) * 16;
            const float* src = gw + (size_t)row * DIM + k0 + seg;
            float4* dst = (float4*)&gs[row*68 + seg];
            #pragma unroll
            for (int j = 0; j < 4; ++j) dst[j] = *(const float4*)(src + j*4);
        }
        __syncthreads();
        #pragma unroll
        for (int k4 = 0; k4 < 16; ++k4) {
            float4 h0 = *(const float4*)&hs[tm*68 + k4*4];
            float4 h1 = *(const float4*)&hs[(tm+16)*68 + k4*4];
            #pragma unroll
            for (int j = 0; j < 4; ++j) {
                float4 g = *(const float4*)&gs[(en + 16*j)*68 + k4*4];
                acc[0][j] += h0.x*g.x + h0.y*g.y + h0.z*g.z + h0.w*g.w;
                acc[1][j] += h1.x*g.x + h1.y*g.y + h1.z*g.z + h1.w*g.w;
            }
        }
        __syncthreads();
    }
    #pragma unroll
    for (int r = 0; r < 2; ++r)
        #pragma unroll
        for (int j = 0; j < 4; ++j)
            logits[(size_t)(t0 + tm + 16*r) * NEXP + en + 16*j] = acc[r][j];
}

// ---------------- softmax + top-8 + scatter (one wave per token) ----------------
__global__ void k_topk(const float* __restrict__ logits, int* __restrict__ counts,
                       int* __restrict__ tlist, float* __restrict__ wlist, int cap) {
    int t = blockIdx.x * 4 + (threadIdx.x >> 6);
    int lane = threadIdx.x & 63;
    float x = logits[(size_t)t * NEXP + lane];

    float m = x;
    #pragma unroll
    for (int off = 32; off; off >>= 1) m = fmaxf(m, __shfl_xor(m, off));
    float p = expf(x - m);
    float s = p;
    #pragma unroll
    for (int off = 32; off; off >>= 1) s += __shfl_xor(s, off);
    float w = p / s;

    float cur = w;
    for (int k = 0; k < TOPK; ++k) {
        float v = cur; int idx = lane;
        #pragma unroll
        for (int off = 32; off; off >>= 1) {
            float ov = __shfl_xor(v, off);
            int   oi = __shfl_xor(idx, off);
            if (ov > v || (ov == v && oi < idx)) { v = ov; idx = oi; }
        }
        if (lane == idx) cur = -1.0f;           // remove winner
        if (lane == 0) {
            int pos = atomicAdd(&counts[idx], 1);
            if (pos < cap) {                     // bounds-guarded scatter
                tlist[(size_t)idx * cap + pos] = t;
                wlist[(size_t)idx * cap + pos] = v;
            }
        }
    }
}

// ---------------- gathered expert GEMM: out[tok,:] += w * (h[tok,:] @ W_e^T) ----------------
#define BM 128
#define BN 128
#define BK 64
#define LDT 72   // LDS stride (bf16 elems), padded: <=2-way (free) conflicts on b128 frag reads

__global__ __launch_bounds__(256) void k_moe(
    const float* __restrict__ h, const float* __restrict__ ew,
    const int* __restrict__ counts, const int* __restrict__ tlist,
    const float* __restrict__ wlist, float* __restrict__ out,
    int cap, int mtiles)
{
    __shared__ short As[BM * LDT];
    __shared__ short Bs[BN * LDT];
    __shared__ int   toks[BM];
    __shared__ float wgts[BM];

    int e  = blockIdx.x / mtiles;
    int mt = blockIdx.x % mtiles;
    int cnt = counts[e];
    if (cnt > cap) cnt = cap;
    if (mt * BM >= cnt) return;
    int n0 = blockIdx.y * BN;
    int tid = threadIdx.x;
    int lane = tid & 63;
    int wv = tid >> 6;
    int wm = wv >> 1, wn = wv & 1;

    if (tid < BM) {
        size_t base = (size_t)e * cap + (size_t)mt * BM + tid;
        toks[tid] = tlist[base];
        wgts[tid] = wlist[base];
    }
    __syncthreads();

    floatx4 acc[4][4];
    #pragma unroll
    for (int i = 0; i < 4; ++i)
        #pragma unroll
        for (int j = 0; j < 4; ++j) acc[i][j] = (floatx4)0.0f;

    int arow = tid >> 1;
    int acol = (tid & 1) * 32;
    const float* hrow  = h  + (size_t)toks[arow] * DIM + acol;
    const float* wbase = ew + ((size_t)e << 20) + (size_t)(n0 + arow) * DIM + acol;

    for (int k0 = 0; k0 < DIM; k0 += BK) {
        // stage A (gathered fp32 h rows -> bf16)
        #pragma unroll
        for (int j = 0; j < 4; ++j) {
            float4 f0 = *(const float4*)(hrow + k0 + j*8);
            float4 f1 = *(const float4*)(hrow + k0 + j*8 + 4);
            short8 o;
            o[0]=f2bf(f0.x); o[1]=f2bf(f0.y); o[2]=f2bf(f0.z); o[3]=f2bf(f0.w);
            o[4]=f2bf(f1.x); o[5]=f2bf(f1.y); o[6]=f2bf(f1.z); o[7]=f2bf(f1.w);
            *(short8*)&As[arow*LDT + acol + j*8] = o;
        }
        // stage B (fp32 W -> bf16)
        #pragma unroll
        for (int j = 0; j < 4; ++j) {
            float4 f0 = *(const float4*)(wbase + k0 + j*8);
            float4 f1 = *(const float4*)(wbase + k0 + j*8 + 4);
            short8 o;
            o[0]=f2bf(f0.x); o[1]=f2bf(f0.y); o[2]=f2bf(f0.z); o[3]=f2bf(f0.w);
            o[4]=f2bf(f1.x); o[5]=f2bf(f1.y); o[6]=f2bf(f1.z); o[7]=f2bf(f1.w);
            *(short8*)&Bs[arow*LDT + acol + j*8] = o;
        }
        __syncthreads();

        #pragma unroll
        for (int s = 0; s < 2; ++s) {
            int ko = s*32 + (lane >> 4) * 8;
            int rr = lane & 15;
            short8 af[4], bfr[4];
            #pragma unroll
            for (int mm = 0; mm < 4; ++mm)
                af[mm] = *(const short8*)&As[(wm*64 + mm*16 + rr)*LDT + ko];
            #pragma unroll
            for (int nn = 0; nn < 4; ++nn)
                bfr[nn] = *(const short8*)&Bs[(wn*64 + nn*16 + rr)*LDT + ko];
            #pragma unroll
            for (int mm = 0; mm < 4; ++mm)
                #pragma unroll
                for (int nn = 0; nn < 4; ++nn)
                    acc[mm][nn] = __builtin_amdgcn_mfma_f32_16x16x32_bf16(
                        af[mm], bfr[nn], acc[mm][nn], 0, 0, 0);
        }
        __syncthreads();
    }

    // epilogue: scale by routing weight, atomic-add into out
    int cgrp = lane >> 4;
    int ccol = lane & 15;
    #pragma unroll
    for (int mm = 0; mm < 4; ++mm) {
        #pragma unroll
        for (int r = 0; r < 4; ++r) {
            int row = wm*64 + mm*16 + cgrp*4 + r;
            float w = wgts[row];
            if (w != 0.0f) {
                size_t tok = (size_t)toks[row];
                #pragma unroll
                for (int nn = 0; nn < 4; ++nn) {
                    int col = n0 + wn*64 + nn*16 + ccol;
                    atomicAdd(&out[tok * DIM + col], w * acc[mm][nn][r]);
                }
            }
        }
    }
}

extern "C" void kernel_launch(void* const* d_in, const int* in_sizes, int n_in,
                              void* d_out, int out_size, void* d_ws, size_t ws_size,
                              hipStream_t stream) {
    const float* h  = (const float*)d_in[0];   // [8192,1024]
    const float* gw = (const float*)d_in[1];   // [64,1024]
    const float* ew = (const float*)d_in[2];   // [64,1024,1024]
    float* out    = (float*)d_out;                       // [8192,1024]
    float* logits = out + (size_t)N_TOK * DIM;           // [8192,64]

    // ---- workspace budget (robust to small ws_size; never write past ws) ----
    size_t avail = (ws_size > 4096) ? (ws_size - 4096) : 0;
    long cap = (long)(avail / ((size_t)NEXP * 8));   // 4B tok + 4B weight per slot
    cap &= ~127L;                                    // multiple of BM
    if (cap > N_TOK) cap = N_TOK;

    char* ws = (char*)d_ws;
    int*   counts = (int*)ws;                                   // 256 B (4 KB reserved)
    int*   tlist  = (int*)(ws + 4096);                          // cap*64*4 B
    float* wlist  = (float*)(ws + 4096 + (size_t)cap*NEXP*4);   // cap*64*4 B

    hipMemsetAsync(out, 0, (size_t)N_TOK*DIM*4, stream);
    k_router<<<dim3(N_TOK/32), 256, 0, stream>>>(h, gw, logits);

    if (cap >= 128) {
        hipMemsetAsync(counts, 0, 256, stream);
        hipMemsetAsync(tlist, 0, (size_t)cap*NEXP*4, stream);   // pad token 0
        hipMemsetAsync(wlist, 0, (size_t)cap*NEXP*4, stream);   // pad weight 0.0f
        k_topk<<<dim3(N_TOK/4), 256, 0, stream>>>(logits, counts, tlist, wlist, (int)cap);
        int mtiles = (int)(cap / BM);
        if (mtiles > N_TOK / BM) mtiles = N_TOK / BM;
        k_moe<<<dim3(NEXP * mtiles, DIM / BN), 256, 0, stream>>>(
            h, ew, counts, tlist, wlist, out, (int)cap, mtiles);
    }
}

// Round 4
// 1078.637 us; speedup vs baseline: 2.6160x; 2.6160x over previous
//
#include <hip/hip_runtime.h>
#include <hip/hip_bf16.h>
#include <math.h>

#define N_TOK 8192
#define DIM   1024
#define NEXP  64
#define TOPK  8

#define BM 256
#define BN 128
#define BK 64
#define LDT 72   // LDS row stride (bf16), <=2-way (free) conflicts on b128 reads

typedef __attribute__((ext_vector_type(8))) short short8;
typedef __attribute__((ext_vector_type(4))) float floatx4;

static __device__ __forceinline__ short f2bf(float f) {
    union { float f; unsigned u; } c; c.f = f;
    unsigned r = c.u + 0x7FFF + ((c.u >> 16) & 1);   // RNE
    return (short)(r >> 16);
}
static __device__ __forceinline__ short8 pack8(float4 a, float4 b) {
    short8 o;
    o[0]=f2bf(a.x); o[1]=f2bf(a.y); o[2]=f2bf(a.z); o[3]=f2bf(a.w);
    o[4]=f2bf(b.x); o[5]=f2bf(b.y); o[6]=f2bf(b.z); o[7]=f2bf(b.w);
    return o;
}

// ---------------- h fp32 -> bf16 (only if ws fits) ----------------
__global__ void k_convert_h(const float* __restrict__ h, short* __restrict__ hb) {
    int i = (blockIdx.x * 256 + threadIdx.x) * 8;
    float4 f0 = *(const float4*)(h + i);
    float4 f1 = *(const float4*)(h + i + 4);
    *(short8*)(hb + i) = pack8(f0, f1);
}

// ---------------- router logits (fp32, known-correct from R3) ----------------
__global__ void k_router(const float* __restrict__ h, const float* __restrict__ gw,
                         float* __restrict__ logits) {
    __shared__ float hs[32 * 68];
    __shared__ float gs[64 * 68];
    int tid = threadIdx.x;
    int t0 = blockIdx.x * 32;
    int tm = tid & 15;
    int en = tid >> 4;
    float acc[2][4] = {{0.f,0.f,0.f,0.f},{0.f,0.f,0.f,0.f}};

    for (int k0 = 0; k0 < DIM; k0 += 64) {
        {
            int row = tid >> 3, seg = (tid & 7) * 8;
            const float* src = h + (size_t)(t0 + row) * DIM + k0 + seg;
            *(float4*)&hs[row*68 + seg]     = *(const float4*)src;
            *(float4*)&hs[row*68 + seg + 4] = *(const float4*)(src + 4);
        }
        {
            int row = tid >> 2, seg = (tid & 3) * 16;
            const float* src = gw + (size_t)row * DIM + k0 + seg;
            float4* dst = (float4*)&gs[row*68 + seg];
            #pragma unroll
            for (int j = 0; j < 4; ++j) dst[j] = *(const float4*)(src + j*4);
        }
        __syncthreads();
        #pragma unroll
        for (int k4 = 0; k4 < 16; ++k4) {
            float4 h0 = *(const float4*)&hs[tm*68 + k4*4];
            float4 h1 = *(const float4*)&hs[(tm+16)*68 + k4*4];
            #pragma unroll
            for (int j = 0; j < 4; ++j) {
                float4 g = *(const float4*)&gs[(en + 16*j)*68 + k4*4];
                acc[0][j] += h0.x*g.x + h0.y*g.y + h0.z*g.z + h0.w*g.w;
                acc[1][j] += h1.x*g.x + h1.y*g.y + h1.z*g.z + h1.w*g.w;
            }
        }
        __syncthreads();
    }
    #pragma unroll
    for (int r = 0; r < 2; ++r)
        #pragma unroll
        for (int j = 0; j < 4; ++j)
            logits[(size_t)(t0 + tm + 16*r) * NEXP + en + 16*j] = acc[r][j];
}

// ---------------- softmax + top-8 + scatter ----------------
__global__ void k_topk(const float* __restrict__ logits, int* __restrict__ counts,
                       int* __restrict__ tlist, float* __restrict__ wlist, int cap) {
    int t = blockIdx.x * 4 + (threadIdx.x >> 6);
    int lane = threadIdx.x & 63;
    float x = logits[(size_t)t * NEXP + lane];

    float m = x;
    #pragma unroll
    for (int off = 32; off; off >>= 1) m = fmaxf(m, __shfl_xor(m, off));
    float p = expf(x - m);
    float s = p;
    #pragma unroll
    for (int off = 32; off; off >>= 1) s += __shfl_xor(s, off);
    float w = p / s;

    float cur = w;
    for (int k = 0; k < TOPK; ++k) {
        float v = cur; int idx = lane;
        #pragma unroll
        for (int off = 32; off; off >>= 1) {
            float ov = __shfl_xor(v, off);
            int   oi = __shfl_xor(idx, off);
            if (ov > v || (ov == v && oi < idx)) { v = ov; idx = oi; }
        }
        if (lane == idx) cur = -1.0f;
        if (lane == 0) {
            int pos = atomicAdd(&counts[idx], 1);
            if (pos < cap) {
                tlist[(size_t)idx * cap + pos] = t;
                wlist[(size_t)idx * cap + pos] = v;
            }
        }
    }
}

// ---------------- gathered expert GEMM, m-loop inside block ----------------
// grid.x = e*8 + nt (512 blocks), 512 threads (8 waves, 2n x 4m wave grid)
template<bool HB>
__global__ __launch_bounds__(512) void k_moe(
    const float* __restrict__ h, const short* __restrict__ hb,
    const float* __restrict__ ew,
    const int* __restrict__ counts, const int* __restrict__ tlist,
    const float* __restrict__ wlist, float* __restrict__ out, int cap)
{
    __shared__ short As[BM * LDT];
    __shared__ short Bs[BN * LDT];
    __shared__ int   toks[BM];
    __shared__ float wgts[BM];

    int e  = blockIdx.x >> 3;
    int n0 = (blockIdx.x & 7) * BN;
    int cnt = counts[e];
    if (cnt > cap) cnt = cap;
    if (cnt == 0) return;
    int ntiles = (cnt + BM - 1) / BM;

    int tid  = threadIdx.x;
    int lane = tid & 63;
    int wv = tid >> 6;        // 0..7
    int wm = wv >> 1;         // 0..3 (m: 64 rows each)
    int wn = wv & 1;          // 0..1 (n: 64 cols each)

    int arow = tid >> 1;            // 0..255
    int acol = (tid & 1) * 32;
    int brow = tid >> 2;            // 0..127
    int bcol = (tid & 3) * 16;
    const float* wbase = ew + ((size_t)e << 20) + (size_t)(n0 + brow) * DIM + bcol;

    float4 raf[8];   // fp32-A prefetch
    uint4  rab[4];   // bf16-A prefetch
    float4 rb[4];    // B prefetch

    for (int mt = 0; mt < ntiles; ++mt) {
        __syncthreads();                       // prev epilogue done with toks/wgts
        if (tid < BM) {
            size_t base = (size_t)e * cap + (size_t)mt * BM + tid;
            toks[tid] = tlist[base];
            wgts[tid] = wlist[base];
        }
        __syncthreads();

        floatx4 acc[4][4];
        #pragma unroll
        for (int i = 0; i < 4; ++i)
            #pragma unroll
            for (int j = 0; j < 4; ++j) acc[i][j] = (floatx4)0.0f;

        const float* hrowf = h  + (size_t)toks[arow] * DIM + acol;
        const short* hrowb = hb + (size_t)toks[arow] * DIM + acol;

        // prefetch k0 = 0
        if constexpr (HB) {
            #pragma unroll
            for (int j = 0; j < 4; ++j) rab[j] = *(const uint4*)(hrowb + j*8);
        } else {
            #pragma unroll
            for (int j = 0; j < 4; ++j) {
                raf[2*j]   = *(const float4*)(hrowf + j*8);
                raf[2*j+1] = *(const float4*)(hrowf + j*8 + 4);
            }
        }
        #pragma unroll
        for (int j = 0; j < 4; ++j) rb[j] = *(const float4*)(wbase + j*4);

        for (int k0 = 0; k0 < DIM; k0 += BK) {
            // store prefetched regs -> LDS (convert to bf16 as needed)
            if constexpr (HB) {
                #pragma unroll
                for (int j = 0; j < 4; ++j)
                    *(uint4*)&As[arow*LDT + acol + j*8] = rab[j];
            } else {
                #pragma unroll
                for (int j = 0; j < 4; ++j)
                    *(short8*)&As[arow*LDT + acol + j*8] = pack8(raf[2*j], raf[2*j+1]);
            }
            #pragma unroll
            for (int j = 0; j < 2; ++j)
                *(short8*)&Bs[brow*LDT + bcol + j*8] = pack8(rb[2*j], rb[2*j+1]);
            __syncthreads();

            // issue next k-step's global loads (overlap with MFMA below)
            int kn = k0 + BK;
            if (kn < DIM) {
                if constexpr (HB) {
                    #pragma unroll
                    for (int j = 0; j < 4; ++j) rab[j] = *(const uint4*)(hrowb + kn + j*8);
                } else {
                    #pragma unroll
                    for (int j = 0; j < 4; ++j) {
                        raf[2*j]   = *(const float4*)(hrowf + kn + j*8);
                        raf[2*j+1] = *(const float4*)(hrowf + kn + j*8 + 4);
                    }
                }
                #pragma unroll
                for (int j = 0; j < 4; ++j) rb[j] = *(const float4*)(wbase + kn + j*4);
            }

            #pragma unroll
            for (int s = 0; s < 2; ++s) {
                int ko = s*32 + (lane >> 4) * 8;
                int rr = lane & 15;
                short8 af[4], bfr[4];
                #pragma unroll
                for (int mm = 0; mm < 4; ++mm)
                    af[mm] = *(const short8*)&As[(wm*64 + mm*16 + rr)*LDT + ko];
                #pragma unroll
                for (int nn = 0; nn < 4; ++nn)
                    bfr[nn] = *(const short8*)&Bs[(wn*64 + nn*16 + rr)*LDT + ko];
                #pragma unroll
                for (int mm = 0; mm < 4; ++mm)
                    #pragma unroll
                    for (int nn = 0; nn < 4; ++nn)
                        acc[mm][nn] = __builtin_amdgcn_mfma_f32_16x16x32_bf16(
                            af[mm], bfr[nn], acc[mm][nn], 0, 0, 0);
            }
            __syncthreads();
        }

        // epilogue: scale by routing weight, atomic-add into out
        int cgrp = lane >> 4;
        int ccol = lane & 15;
        #pragma unroll
        for (int mm = 0; mm < 4; ++mm) {
            #pragma unroll
            for (int r = 0; r < 4; ++r) {
                int row = wm*64 + mm*16 + cgrp*4 + r;
                float w = wgts[row];
                if (w != 0.0f) {
                    size_t tok = (size_t)toks[row];
                    #pragma unroll
                    for (int nn = 0; nn < 4; ++nn) {
                        int col = n0 + wn*64 + nn*16 + ccol;
                        atomicAdd(&out[tok * DIM + col], w * acc[mm][nn][r]);
                    }
                }
            }
        }
    }
}

extern "C" void kernel_launch(void* const* d_in, const int* in_sizes, int n_in,
                              void* d_out, int out_size, void* d_ws, size_t ws_size,
                              hipStream_t stream) {
    const float* h  = (const float*)d_in[0];   // [8192,1024]
    const float* gw = (const float*)d_in[1];   // [64,1024]
    const float* ew = (const float*)d_in[2];   // [64,1024,1024]
    float* out    = (float*)d_out;                       // [8192,1024]
    float* logits = out + (size_t)N_TOK * DIM;           // [8192,64]

    // ---- workspace budget (never write past ws) ----
    size_t avail = (ws_size > 4096) ? (ws_size - 4096) : 0;
    long cap = (long)(avail / ((size_t)NEXP * 8));
    cap &= ~255L;                       // multiple of BM
    if (cap > N_TOK) cap = N_TOK;

    char* ws = (char*)d_ws;
    int*   counts = (int*)ws;                                   // 4 KB reserved
    int*   tlist  = (int*)(ws + 4096);
    float* wlist  = (float*)(ws + 4096 + (size_t)cap*NEXP*4);
    size_t hb_off = 4096 + 2*(size_t)cap*NEXP*4;
    bool use_hb = (cap >= 256) && (ws_size >= hb_off + (size_t)N_TOK*DIM*2);
    short* hbuf = (short*)(ws + hb_off);

    hipMemsetAsync(out, 0, (size_t)N_TOK*DIM*4, stream);
    k_router<<<dim3(N_TOK/32), 256, 0, stream>>>(h, gw, logits);

    if (cap >= 256) {
        hipMemsetAsync(counts, 0, 256, stream);
        hipMemsetAsync(tlist, 0, (size_t)cap*NEXP*4, stream);   // pad token 0
        hipMemsetAsync(wlist, 0, (size_t)cap*NEXP*4, stream);   // pad weight 0.0f
        k_topk<<<dim3(N_TOK/4), 256, 0, stream>>>(logits, counts, tlist, wlist, (int)cap);
        if (use_hb) {
            k_convert_h<<<dim3((N_TOK*DIM)/(256*8)), 256, 0, stream>>>(h, hbuf);
            k_moe<true><<<dim3(NEXP*8), 512, 0, stream>>>(
                h, hbuf, ew, counts, tlist, wlist, out, (int)cap);
        } else {
            k_moe<false><<<dim3(NEXP*8), 512, 0, stream>>>(
                h, hbuf, ew, counts, tlist, wlist, out, (int)cap);
        }
    }
}

// Round 5
// 790.976 us; speedup vs baseline: 3.5673x; 1.3637x over previous
//
#include <hip/hip_runtime.h>
#include <hip/hip_bf16.h>
#include <math.h>

#define N_TOK 8192
#define DIM   1024
#define NEXP  64
#define TOPK  8
#define CAPF  2048     // per-expert list capacity (mean load 1024, 32 sigma headroom)

#define BM 256
#define BN 128
#define BK 64
#define LDT 72   // LDS row stride (bf16): b128 frag reads land 2-way (free) conflicts

typedef __attribute__((ext_vector_type(8))) short short8;
typedef __attribute__((ext_vector_type(4))) float floatx4;
typedef __attribute__((ext_vector_type(4))) unsigned short ushort4v;

static __device__ __forceinline__ short f2bf(float f) {
    union { float f; unsigned u; } c; c.f = f;
    unsigned r = c.u + 0x7FFF + ((c.u >> 16) & 1);   // RNE
    return (short)(r >> 16);
}
static __device__ __forceinline__ float bf2f(unsigned short s) {
    union { unsigned u; float f; } c; c.u = ((unsigned)s) << 16;
    return c.f;
}
static __device__ __forceinline__ short8 pack8(float4 a, float4 b) {
    short8 o;
    o[0]=f2bf(a.x); o[1]=f2bf(a.y); o[2]=f2bf(a.z); o[3]=f2bf(a.w);
    o[4]=f2bf(b.x); o[5]=f2bf(b.y); o[6]=f2bf(b.z); o[7]=f2bf(b.w);
    return o;
}

// ---------------- fp32 -> bf16 bulk convert (8 elems/thread) ----------------
__global__ void k_convert(const float* __restrict__ src, short* __restrict__ dst) {
    size_t i = ((size_t)blockIdx.x * 256 + threadIdx.x) * 8;
    float4 f0 = *(const float4*)(src + i);
    float4 f1 = *(const float4*)(src + i + 4);
    *(short8*)(dst + i) = pack8(f0, f1);
}

// ---------------- router logits (fp32, known-correct) ----------------
__global__ void k_router(const float* __restrict__ h, const float* __restrict__ gw,
                         float* __restrict__ logits) {
    __shared__ float hs[32 * 68];
    __shared__ float gs[64 * 68];
    int tid = threadIdx.x;
    int t0 = blockIdx.x * 32;
    int tm = tid & 15;
    int en = tid >> 4;
    float acc[2][4] = {{0.f,0.f,0.f,0.f},{0.f,0.f,0.f,0.f}};

    for (int k0 = 0; k0 < DIM; k0 += 64) {
        {
            int row = tid >> 3, seg = (tid & 7) * 8;
            const float* src = h + (size_t)(t0 + row) * DIM + k0 + seg;
            *(float4*)&hs[row*68 + seg]     = *(const float4*)src;
            *(float4*)&hs[row*68 + seg + 4] = *(const float4*)(src + 4);
        }
        {
            int row = tid >> 2, seg = (tid & 3) * 16;
            const float* src = gw + (size_t)row * DIM + k0 + seg;
            float4* dst = (float4*)&gs[row*68 + seg];
            #pragma unroll
            for (int j = 0; j < 4; ++j) dst[j] = *(const float4*)(src + j*4);
        }
        __syncthreads();
        #pragma unroll
        for (int k4 = 0; k4 < 16; ++k4) {
            float4 h0 = *(const float4*)&hs[tm*68 + k4*4];
            float4 h1 = *(const float4*)&hs[(tm+16)*68 + k4*4];
            #pragma unroll
            for (int j = 0; j < 4; ++j) {
                float4 g = *(const float4*)&gs[(en + 16*j)*68 + k4*4];
                acc[0][j] += h0.x*g.x + h0.y*g.y + h0.z*g.z + h0.w*g.w;
                acc[1][j] += h1.x*g.x + h1.y*g.y + h1.z*g.z + h1.w*g.w;
            }
        }
        __syncthreads();
    }
    #pragma unroll
    for (int r = 0; r < 2; ++r)
        #pragma unroll
        for (int j = 0; j < 4; ++j)
            logits[(size_t)(t0 + tm + 16*r) * NEXP + en + 16*j] = acc[r][j];
}

// ---------------- phase 1: per-token softmax + top-8 (no atomics) ----------------
__global__ void k_topk1(const float* __restrict__ logits,
                        int* __restrict__ tki, float* __restrict__ tkw) {
    int t = blockIdx.x * 4 + (threadIdx.x >> 6);
    int lane = threadIdx.x & 63;
    float x = logits[(size_t)t * NEXP + lane];

    float m = x;
    #pragma unroll
    for (int off = 32; off; off >>= 1) m = fmaxf(m, __shfl_xor(m, off));
    float p = expf(x - m);
    float s = p;
    #pragma unroll
    for (int off = 32; off; off >>= 1) s += __shfl_xor(s, off);
    float w = p / s;

    float cur = w;
    for (int k = 0; k < TOPK; ++k) {
        float v = cur; int idx = lane;
        #pragma unroll
        for (int off = 32; off; off >>= 1) {
            float ov = __shfl_xor(v, off);
            int   oi = __shfl_xor(idx, off);
            if (ov > v || (ov == v && oi < idx)) { v = ov; idx = oi; }
        }
        if (lane == idx) cur = -1.0f;
        if (lane == 0) {
            tki[(size_t)t * TOPK + k] = idx;
            tkw[(size_t)t * TOPK + k] = v;
        }
    }
}

// ---------------- phase 2: compaction into token-sorted per-expert lists ----------------
// one block per expert; tlist stores SLOT = t*8 + rank
__global__ void k_topk2(const int* __restrict__ tki, const float* __restrict__ tkw,
                        int* __restrict__ counts, int* __restrict__ tlist,
                        float* __restrict__ wlist, int cap) {
    int e = blockIdx.x, tid = threadIdx.x, lane = tid & 63, wv = tid >> 6;
    __shared__ int wtot[4];
    __shared__ int carry_s;
    if (tid == 0) carry_s = 0;
    __syncthreads();

    for (int c0 = 0; c0 < N_TOK * TOPK; c0 += 1024) {
        int i = c0 + tid * 4;
        int4 v = *(const int4*)(tki + i);
        int m0 = (v.x == e), m1 = (v.y == e), m2 = (v.z == e), m3 = (v.w == e);
        int mc = m0 + m1 + m2 + m3;
        int sc = mc;
        #pragma unroll
        for (int off = 1; off < 64; off <<= 1) {
            int o = __shfl_up(sc, off);
            if (lane >= off) sc += o;
        }
        if (lane == 63) wtot[wv] = sc;
        int excl = sc - mc;
        __syncthreads();
        int wbase = 0;
        #pragma unroll
        for (int j = 0; j < 4; ++j) if (j < wv) wbase += wtot[j];
        int tot = wtot[0] + wtot[1] + wtot[2] + wtot[3];
        int pos = carry_s + wbase + excl;
        if (m0) { if (pos < cap) { tlist[(size_t)e*cap+pos] = i;   wlist[(size_t)e*cap+pos] = tkw[i];   } pos++; }
        if (m1) { if (pos < cap) { tlist[(size_t)e*cap+pos] = i+1; wlist[(size_t)e*cap+pos] = tkw[i+1]; } pos++; }
        if (m2) { if (pos < cap) { tlist[(size_t)e*cap+pos] = i+2; wlist[(size_t)e*cap+pos] = tkw[i+2]; } pos++; }
        if (m3) { if (pos < cap) { tlist[(size_t)e*cap+pos] = i+3; wlist[(size_t)e*cap+pos] = tkw[i+3]; } pos++; }
        __syncthreads();
        if (tid == 0) carry_s += tot;
        __syncthreads();
    }
    if (tid == 0) counts[e] = min(carry_s, cap);
}

// ---------------- gathered expert GEMM ----------------
// grid.x = e*8 + nt, 512 threads (8 waves: 4m x 2n). AB: bf16 A src; WB: bf16 W src;
// CT: store bf16 contrib rows (no atomics) vs atomicAdd into out.
template<bool AB, bool WB, bool CT>
__global__ __launch_bounds__(512) void k_moe(
    const float* __restrict__ h, const short* __restrict__ hb,
    const float* __restrict__ ew, const short* __restrict__ wb,
    const int* __restrict__ counts, const int* __restrict__ tlist,
    const float* __restrict__ wlist, float* __restrict__ out,
    unsigned short* __restrict__ contrib, int cap)
{
    __shared__ short As[BM * LDT];
    __shared__ short Bs[BN * LDT];
    __shared__ int   slots[BM];
    __shared__ float wgts[BM];

    int e  = blockIdx.x >> 3;
    int n0 = (blockIdx.x & 7) * BN;
    int cnt = counts[e];
    if (cnt > cap) cnt = cap;
    if (cnt == 0) return;
    int ntiles = (cnt + BM - 1) / BM;

    int tid  = threadIdx.x;
    int lane = tid & 63;
    int wv = tid >> 6;
    int wm = wv >> 1;         // 0..3
    int wn = wv & 1;          // 0..1

    int arow = tid >> 1;            // 0..255
    int acol = (tid & 1) * 32;
    int brow = tid >> 2;            // 0..127
    int bcol = (tid & 3) * 16;
    const float* wbasef = ew + ((size_t)e << 20) + (size_t)(n0 + brow) * DIM + bcol;
    const short* wbaseb = wb + ((size_t)e << 20) + (size_t)(n0 + brow) * DIM + bcol;

    float4 raf[8];
    uint4  rab[4];
    float4 rbf[4];
    uint4  rbb[2];

    for (int mt = 0; mt < ntiles; ++mt) {
        __syncthreads();
        if (tid < BM) {
            size_t base = (size_t)e * cap + (size_t)mt * BM + tid;
            slots[tid] = tlist[base];
            wgts[tid]  = wlist[base];
        }
        __syncthreads();

        floatx4 acc[4][4];
        #pragma unroll
        for (int i = 0; i < 4; ++i)
            #pragma unroll
            for (int j = 0; j < 4; ++j) acc[i][j] = (floatx4)0.0f;

        size_t trow = (size_t)(slots[arow] >> 3);
        const float* hrowf = h  + trow * DIM + acol;
        const short* hrowb = hb + trow * DIM + acol;

        // prefetch k0 = 0
        if constexpr (AB) {
            #pragma unroll
            for (int j = 0; j < 4; ++j) rab[j] = *(const uint4*)(hrowb + j*8);
        } else {
            #pragma unroll
            for (int j = 0; j < 4; ++j) {
                raf[2*j]   = *(const float4*)(hrowf + j*8);
                raf[2*j+1] = *(const float4*)(hrowf + j*8 + 4);
            }
        }
        if constexpr (WB) {
            #pragma unroll
            for (int j = 0; j < 2; ++j) rbb[j] = *(const uint4*)(wbaseb + j*8);
        } else {
            #pragma unroll
            for (int j = 0; j < 4; ++j) rbf[j] = *(const float4*)(wbasef + j*4);
        }

        for (int k0 = 0; k0 < DIM; k0 += BK) {
            if constexpr (AB) {
                #pragma unroll
                for (int j = 0; j < 4; ++j)
                    *(uint4*)&As[arow*LDT + acol + j*8] = rab[j];
            } else {
                #pragma unroll
                for (int j = 0; j < 4; ++j)
                    *(short8*)&As[arow*LDT + acol + j*8] = pack8(raf[2*j], raf[2*j+1]);
            }
            if constexpr (WB) {
                #pragma unroll
                for (int j = 0; j < 2; ++j)
                    *(uint4*)&Bs[brow*LDT + bcol + j*8] = rbb[j];
            } else {
                #pragma unroll
                for (int j = 0; j < 2; ++j)
                    *(short8*)&Bs[brow*LDT + bcol + j*8] = pack8(rbf[2*j], rbf[2*j+1]);
            }
            __syncthreads();

            int kn = k0 + BK;
            if (kn < DIM) {
                if constexpr (AB) {
                    #pragma unroll
                    for (int j = 0; j < 4; ++j) rab[j] = *(const uint4*)(hrowb + kn + j*8);
                } else {
                    #pragma unroll
                    for (int j = 0; j < 4; ++j) {
                        raf[2*j]   = *(const float4*)(hrowf + kn + j*8);
                        raf[2*j+1] = *(const float4*)(hrowf + kn + j*8 + 4);
                    }
                }
                if constexpr (WB) {
                    #pragma unroll
                    for (int j = 0; j < 2; ++j) rbb[j] = *(const uint4*)(wbaseb + kn + j*8);
                } else {
                    #pragma unroll
                    for (int j = 0; j < 4; ++j) rbf[j] = *(const float4*)(wbasef + kn + j*4);
                }
            }

            #pragma unroll
            for (int s = 0; s < 2; ++s) {
                int ko = s*32 + (lane >> 4) * 8;
                int rr = lane & 15;
                short8 af[4], bfr[4];
                #pragma unroll
                for (int mm = 0; mm < 4; ++mm)
                    af[mm] = *(const short8*)&As[(wm*64 + mm*16 + rr)*LDT + ko];
                #pragma unroll
                for (int nn = 0; nn < 4; ++nn)
                    bfr[nn] = *(const short8*)&Bs[(wn*64 + nn*16 + rr)*LDT + ko];
                #pragma unroll
                for (int mm = 0; mm < 4; ++mm)
                    #pragma unroll
                    for (int nn = 0; nn < 4; ++nn)
                        acc[mm][nn] = __builtin_amdgcn_mfma_f32_16x16x32_bf16(
                            af[mm], bfr[nn], acc[mm][nn], 0, 0, 0);
            }
            __syncthreads();
        }

        // epilogue
        int cgrp = lane >> 4;
        int ccol = lane & 15;
        #pragma unroll
        for (int mm = 0; mm < 4; ++mm) {
            #pragma unroll
            for (int r = 0; r < 4; ++r) {
                int row = wm*64 + mm*16 + cgrp*4 + r;
                float w = wgts[row];
                if (w != 0.0f) {
                    if constexpr (CT) {
                        size_t base = (size_t)slots[row] * DIM + n0 + wn*64;
                        #pragma unroll
                        for (int nn = 0; nn < 4; ++nn)
                            contrib[base + nn*16 + ccol] =
                                (unsigned short)f2bf(w * acc[mm][nn][r]);
                    } else {
                        size_t tok = (size_t)(slots[row] >> 3);
                        #pragma unroll
                        for (int nn = 0; nn < 4; ++nn) {
                            int col = n0 + wn*64 + nn*16 + ccol;
                            atomicAdd(&out[tok * DIM + col], w * acc[mm][nn][r]);
                        }
                    }
                }
            }
        }
    }
}

// ---------------- gather: out[t] = sum_k contrib[t*8+k] ----------------
__global__ void k_gather(const unsigned short* __restrict__ contrib,
                         float* __restrict__ out) {
    int t = blockIdx.x;
    int c = threadIdx.x * 4;
    float4 s = {0.f, 0.f, 0.f, 0.f};
    #pragma unroll
    for (int k = 0; k < TOPK; ++k) {
        ushort4v v = *(const ushort4v*)(contrib + ((size_t)t * TOPK + k) * DIM + c);
        s.x += bf2f(v[0]); s.y += bf2f(v[1]); s.z += bf2f(v[2]); s.w += bf2f(v[3]);
    }
    *(float4*)(out + (size_t)t * DIM + c) = s;
}

extern "C" void kernel_launch(void* const* d_in, const int* in_sizes, int n_in,
                              void* d_out, int out_size, void* d_ws, size_t ws_size,
                              hipStream_t stream) {
    const float* h  = (const float*)d_in[0];   // [8192,1024]
    const float* gw = (const float*)d_in[1];   // [64,1024]
    const float* ew = (const float*)d_in[2];   // [64,1024,1024]
    float* out    = (float*)d_out;
    float* logits = out + (size_t)N_TOK * DIM;

    const size_t SZ_TK   = (size_t)N_TOK * TOPK * 4;         // 256 KiB
    const size_t SZ_HB   = (size_t)N_TOK * DIM * 2;          // 16 MiB
    const size_t SZ_WB   = (size_t)NEXP * DIM * DIM * 2;     // 128 MiB
    const size_t SZ_CT   = (size_t)N_TOK * TOPK * DIM * 2;   // 128 MiB
    const size_t SZ_LIST = (size_t)CAPF * NEXP * 4;          // 512 KiB each

    // tier thresholds
    size_t need_base = 4096 + 2*SZ_LIST + 2*SZ_TK + SZ_HB;
    size_t need_t1   = need_base + SZ_WB;
    size_t need_t2   = need_t1 + SZ_CT;

    int tier;
    long cap = CAPF;
    if      (ws_size >= need_t2)   tier = 3;   // bf16 A+W, contrib store
    else if (ws_size >= need_t1)   tier = 2;   // bf16 A+W, atomics
    else if (ws_size >= need_base) tier = 1;   // bf16 A, fp32 W, atomics
    else {                                      // fp32 A+W, atomics, derived cap
        tier = 0;
        size_t avail = (ws_size > 4096 + 2*SZ_TK) ? ws_size - 4096 - 2*SZ_TK : 0;
        cap = (long)(avail / ((size_t)NEXP * 8));
        cap &= ~255L;
        if (cap > N_TOK) cap = N_TOK;
    }

    char* ws = (char*)d_ws;
    size_t off = 0;
    int*   counts = (int*)(ws + off);  off += 4096;
    int*   tlist  = (int*)(ws + off);  off += (size_t)cap * NEXP * 4;
    float* wlist  = (float*)(ws + off); off += (size_t)cap * NEXP * 4;
    int*   tki    = (int*)(ws + off);  off += SZ_TK;
    float* tkw    = (float*)(ws + off); off += SZ_TK;
    short* hb     = (short*)(ws + off); if (tier >= 1) off += SZ_HB;
    short* wbuf   = (short*)(ws + off); if (tier >= 2) off += SZ_WB;
    unsigned short* contrib = (unsigned short*)(ws + off);

    k_router<<<dim3(N_TOK/32), 256, 0, stream>>>(h, gw, logits);

    if (cap < 256) return;   // ws unusably small: logits correct, out will fail loudly

    hipMemsetAsync(counts, 0, 256, stream);
    hipMemsetAsync(tlist, 0, (size_t)cap*NEXP*4, stream);   // pad slot 0
    hipMemsetAsync(wlist, 0, (size_t)cap*NEXP*4, stream);   // pad weight 0.0f
    if (tier < 3) hipMemsetAsync(out, 0, (size_t)N_TOK*DIM*4, stream);

    if (tier >= 1)
        k_convert<<<dim3((N_TOK*DIM)/(256*8)), 256, 0, stream>>>(h, hb);
    if (tier >= 2)
        k_convert<<<dim3((unsigned)((size_t)NEXP*DIM*DIM/(256*8))), 256, 0, stream>>>(ew, wbuf);

    k_topk1<<<dim3(N_TOK/4), 256, 0, stream>>>(logits, tki, tkw);
    k_topk2<<<dim3(NEXP), 256, 0, stream>>>(tki, tkw, counts, tlist, wlist, (int)cap);

    dim3 mg(NEXP * 8);
    if (tier == 3) {
        k_moe<true,true,true><<<mg, 512, 0, stream>>>(
            h, hb, ew, wbuf, counts, tlist, wlist, out, contrib, (int)cap);
        k_gather<<<dim3(N_TOK), 256, 0, stream>>>(contrib, out);
    } else if (tier == 2) {
        k_moe<true,true,false><<<mg, 512, 0, stream>>>(
            h, hb, ew, wbuf, counts, tlist, wlist, out, contrib, (int)cap);
    } else if (tier == 1) {
        k_moe<true,false,false><<<mg, 512, 0, stream>>>(
            h, hb, ew, wbuf, counts, tlist, wlist, out, contrib, (int)cap);
    } else {
        k_moe<false,false,false><<<mg, 512, 0, stream>>>(
            h, hb, ew, wbuf, counts, tlist, wlist, out, contrib, (int)cap);
    }
}

// Round 6
// 521.960 us; speedup vs baseline: 5.4059x; 1.5154x over previous
//
#include <hip/hip_runtime.h>
#include <hip/hip_bf16.h>
#include <math.h>

#define N_TOK 8192
#define DIM   1024
#define NEXP  64
#define TOPK  8
#define CAPF  2048     // per-expert list capacity (mean 1024, ~34 sigma headroom)

typedef __attribute__((ext_vector_type(8))) short short8;
typedef __attribute__((ext_vector_type(4))) float floatx4;
typedef __attribute__((ext_vector_type(4))) unsigned short ushort4v;
typedef unsigned int u32;

static __device__ __forceinline__ short f2bf(float f) {
    union { float f; unsigned u; } c; c.f = f;
    unsigned r = c.u + 0x7FFF + ((c.u >> 16) & 1);   // RNE
    return (short)(r >> 16);
}
static __device__ __forceinline__ float bf2f(unsigned short s) {
    union { unsigned u; float f; } c; c.u = ((unsigned)s) << 16;
    return c.f;
}
static __device__ __forceinline__ short8 pack8(float4 a, float4 b) {
    short8 o;
    o[0]=f2bf(a.x); o[1]=f2bf(a.y); o[2]=f2bf(a.z); o[3]=f2bf(a.w);
    o[4]=f2bf(b.x); o[5]=f2bf(b.y); o[6]=f2bf(b.z); o[7]=f2bf(b.w);
    return o;
}
// async global->LDS, 16B per lane; lds ptr must be wave-uniform (HW: base + lane*16)
static __device__ __forceinline__ void gll16(const short* g, short* l) {
    __builtin_amdgcn_global_load_lds(
        (const __attribute__((address_space(1))) u32*)(const void*)g,
        (__attribute__((address_space(3))) u32*)(void*)l, 16, 0, 0);
}

// ---------------- fp32 -> bf16 bulk convert (8 elems/thread) ----------------
__global__ void k_convert(const float* __restrict__ src, short* __restrict__ dst) {
    size_t i = ((size_t)blockIdx.x * 256 + threadIdx.x) * 8;
    float4 f0 = *(const float4*)(src + i);
    float4 f1 = *(const float4*)(src + i + 4);
    *(short8*)(dst + i) = pack8(f0, f1);
}

// ---------------- router logits (fp32, known-correct) ----------------
__global__ void k_router(const float* __restrict__ h, const float* __restrict__ gw,
                         float* __restrict__ logits) {
    __shared__ float hs[32 * 68];
    __shared__ float gs[64 * 68];
    int tid = threadIdx.x;
    int t0 = blockIdx.x * 32;
    int tm = tid & 15;
    int en = tid >> 4;
    float acc[2][4] = {{0.f,0.f,0.f,0.f},{0.f,0.f,0.f,0.f}};

    for (int k0 = 0; k0 < DIM; k0 += 64) {
        {
            int row = tid >> 3, seg = (tid & 7) * 8;
            const float* src = h + (size_t)(t0 + row) * DIM + k0 + seg;
            *(float4*)&hs[row*68 + seg]     = *(const float4*)src;
            *(float4*)&hs[row*68 + seg + 4] = *(const float4*)(src + 4);
        }
        {
            int row = tid >> 2, seg = (tid & 3) * 16;
            const float* src = gw + (size_t)row * DIM + k0 + seg;
            float4* dst = (float4*)&gs[row*68 + seg];
            #pragma unroll
            for (int j = 0; j < 4; ++j) dst[j] = *(const float4*)(src + j*4);
        }
        __syncthreads();
        #pragma unroll
        for (int k4 = 0; k4 < 16; ++k4) {
            float4 h0 = *(const float4*)&hs[tm*68 + k4*4];
            float4 h1 = *(const float4*)&hs[(tm+16)*68 + k4*4];
            #pragma unroll
            for (int j = 0; j < 4; ++j) {
                float4 g = *(const float4*)&gs[(en + 16*j)*68 + k4*4];
                acc[0][j] += h0.x*g.x + h0.y*g.y + h0.z*g.z + h0.w*g.w;
                acc[1][j] += h1.x*g.x + h1.y*g.y + h1.z*g.z + h1.w*g.w;
            }
        }
        __syncthreads();
    }
    #pragma unroll
    for (int r = 0; r < 2; ++r)
        #pragma unroll
        for (int j = 0; j < 4; ++j)
            logits[(size_t)(t0 + tm + 16*r) * NEXP + en + 16*j] = acc[r][j];
}

// ---------------- phase 1: per-token softmax + top-8 ----------------
__global__ void k_topk1(const float* __restrict__ logits,
                        int* __restrict__ tki, float* __restrict__ tkw) {
    int t = blockIdx.x * 4 + (threadIdx.x >> 6);
    int lane = threadIdx.x & 63;
    float x = logits[(size_t)t * NEXP + lane];

    float m = x;
    #pragma unroll
    for (int off = 32; off; off >>= 1) m = fmaxf(m, __shfl_xor(m, off));
    float p = expf(x - m);
    float s = p;
    #pragma unroll
    for (int off = 32; off; off >>= 1) s += __shfl_xor(s, off);
    float w = p / s;

    float cur = w;
    for (int k = 0; k < TOPK; ++k) {
        float v = cur; int idx = lane;
        #pragma unroll
        for (int off = 32; off; off >>= 1) {
            float ov = __shfl_xor(v, off);
            int   oi = __shfl_xor(idx, off);
            if (ov > v || (ov == v && oi < idx)) { v = ov; idx = oi; }
        }
        if (lane == idx) cur = -1.0f;
        if (lane == 0) {
            tki[(size_t)t * TOPK + k] = idx;
            tkw[(size_t)t * TOPK + k] = v;
        }
    }
}

// ---------------- phase 2: compaction into token-sorted per-expert lists ----------------
__global__ void k_topk2(const int* __restrict__ tki, const float* __restrict__ tkw,
                        int* __restrict__ counts, int* __restrict__ tlist,
                        float* __restrict__ wlist, int cap) {
    int e = blockIdx.x, tid = threadIdx.x, lane = tid & 63, wv = tid >> 6;
    __shared__ int wtot[4];
    __shared__ int carry_s;
    if (tid == 0) carry_s = 0;
    __syncthreads();

    for (int c0 = 0; c0 < N_TOK * TOPK; c0 += 1024) {
        int i = c0 + tid * 4;
        int4 v = *(const int4*)(tki + i);
        int m0 = (v.x == e), m1 = (v.y == e), m2 = (v.z == e), m3 = (v.w == e);
        int mc = m0 + m1 + m2 + m3;
        int sc = mc;
        #pragma unroll
        for (int off = 1; off < 64; off <<= 1) {
            int o = __shfl_up(sc, off);
            if (lane >= off) sc += o;
        }
        if (lane == 63) wtot[wv] = sc;
        int excl = sc - mc;
        __syncthreads();
        int wbase = 0;
        #pragma unroll
        for (int j = 0; j < 4; ++j) if (j < wv) wbase += wtot[j];
        int tot = wtot[0] + wtot[1] + wtot[2] + wtot[3];
        int pos = carry_s + wbase + excl;
        if (m0) { if (pos < cap) { tlist[(size_t)e*cap+pos] = i;   wlist[(size_t)e*cap+pos] = tkw[i];   } pos++; }
        if (m1) { if (pos < cap) { tlist[(size_t)e*cap+pos] = i+1; wlist[(size_t)e*cap+pos] = tkw[i+1]; } pos++; }
        if (m2) { if (pos < cap) { tlist[(size_t)e*cap+pos] = i+2; wlist[(size_t)e*cap+pos] = tkw[i+2]; } pos++; }
        if (m3) { if (pos < cap) { tlist[(size_t)e*cap+pos] = i+3; wlist[(size_t)e*cap+pos] = tkw[i+3]; } pos++; }
        __syncthreads();
        if (tid == 0) carry_s += tot;
        __syncthreads();
    }
    if (tid == 0) counts[e] = min(carry_s, cap);
}

// ================= tier-3 fast path: 128x128 tile, global_load_lds, swizzled =================
// grid.x = mt*512 + e*8 + nt  (mt-major: the 16 m-tile blocks sharing a W slice -> same XCD)
#define PADW 136
__global__ __launch_bounds__(256) void k_moe3(
    const short* __restrict__ hb, const short* __restrict__ wb,
    const int* __restrict__ counts, const int* __restrict__ tlist,
    const float* __restrict__ wlist, unsigned short* __restrict__ contrib, int cap)
{
    __shared__ short As[128 * 64];     // linear, chunk-swizzled: pos(row,c) holds global chunk c^(row&7)
    __shared__ short Bs[128 * 64];
    __shared__ int   slots[128];
    __shared__ float wgts[128];

    int bx = blockIdx.x;
    int mt = bx >> 9;
    int en = bx & 511;
    int e  = en >> 3;
    int n0 = (en & 7) * 128;
    int cnt = counts[e]; if (cnt > cap) cnt = cap;
    if (mt * 128 >= cnt) return;

    int tid = threadIdx.x, lane = tid & 63, w = tid >> 6;
    int wm = w >> 1, wn = w & 1;

    if (tid < 128) {
        size_t base = (size_t)e * cap + (size_t)mt * 128 + tid;
        slots[tid] = tlist[base];
        wgts[tid]  = wlist[base];
    }
    __syncthreads();

    // per-lane global source addresses (pre-swizzled chunk)
    const short* aaddr[4];
    const short* baddr[4];
    #pragma unroll
    for (int i = 0; i < 4; ++i) {
        int row = (w*4 + i)*8 + (lane >> 3);
        int g   = (lane & 7) ^ (row & 7);
        int tok = slots[row] >> 3;
        aaddr[i] = hb + (size_t)tok * DIM + g*8;
        baddr[i] = wb + ((size_t)e << 20) + (size_t)(n0 + row) * DIM + g*8;
    }

    floatx4 acc[4][4];
    #pragma unroll
    for (int i = 0; i < 4; ++i)
        #pragma unroll
        for (int j = 0; j < 4; ++j) acc[i][j] = (floatx4)0.0f;

    for (int ks = 0; ks < 16; ++ks) {
        #pragma unroll
        for (int i = 0; i < 4; ++i) {
            gll16(aaddr[i], &As[(w*4 + i) * 512]);
            gll16(baddr[i], &Bs[(w*4 + i) * 512]);
            aaddr[i] += 64; baddr[i] += 64;
        }
        __syncthreads();   // drains vmcnt -> tile resident

        #pragma unroll
        for (int s = 0; s < 2; ++s) {
            int gch = s*4 + (lane >> 4);
            int rr  = lane & 15;
            short8 af[4], bfr[4];
            #pragma unroll
            for (int mm = 0; mm < 4; ++mm) {
                int row = wm*64 + mm*16 + rr;
                af[mm] = *(const short8*)&As[row*64 + ((gch ^ (row & 7)) * 8)];
            }
            #pragma unroll
            for (int nn = 0; nn < 4; ++nn) {
                int row = wn*64 + nn*16 + rr;
                bfr[nn] = *(const short8*)&Bs[row*64 + ((gch ^ (row & 7)) * 8)];
            }
            #pragma unroll
            for (int mm = 0; mm < 4; ++mm)
                #pragma unroll
                for (int nn = 0; nn < 4; ++nn)
                    acc[mm][nn] = __builtin_amdgcn_mfma_f32_16x16x32_bf16(
                        af[mm], bfr[nn], acc[mm][nn], 0, 0, 0);
        }
        __syncthreads();   // reads done before next stage overwrites
    }

    // epilogue: LDS transpose (reuse As) -> 32B-contiguous bf16 stores
    short* pad = As;       // needs 32*PADW = 4352 shorts <= 8192
    int cgrp = lane >> 4, ccol = lane & 15;
    #pragma unroll
    for (int mm = 0; mm < 4; ++mm) {
        __syncthreads();   // pad free (prev mm readers / k-loop done)
        #pragma unroll
        for (int r = 0; r < 4; ++r) {
            int sub = cgrp*4 + r;
            float wgt = wgts[wm*64 + mm*16 + sub];
            #pragma unroll
            for (int nn = 0; nn < 4; ++nn)
                pad[(wm*16 + sub)*PADW + wn*64 + nn*16 + ccol] =
                    f2bf(wgt * acc[mm][nn][r]);
        }
        __syncthreads();
        int rr = tid >> 3, ch = tid & 7;       // 32 rows x 8 chunks of 16 shorts
        int wm2 = rr >> 4, sub = rr & 15;
        int grow = wm2*64 + mm*16 + sub;
        if (wgts[grow] != 0.0f) {
            size_t base = (size_t)slots[grow] * DIM + n0 + ch*16;
            uint4 v0 = *(const uint4*)&pad[rr*PADW + ch*16];
            uint4 v1 = *(const uint4*)&pad[rr*PADW + ch*16 + 8];
            *(uint4*)&contrib[base]     = v0;
            *(uint4*)&contrib[base + 8] = v1;
        }
    }
}

// ---------------- fallback gathered GEMM (tiers 0-2, atomics) ----------------
#define BMo 256
#define BNo 128
#define LDT 72
template<bool AB, bool WB>
__global__ __launch_bounds__(512) void k_moe(
    const float* __restrict__ h, const short* __restrict__ hb,
    const float* __restrict__ ew, const short* __restrict__ wb,
    const int* __restrict__ counts, const int* __restrict__ tlist,
    const float* __restrict__ wlist, float* __restrict__ out, int cap)
{
    __shared__ short As[BMo * LDT];
    __shared__ short Bs[BNo * LDT];
    __shared__ int   slots[BMo];
    __shared__ float wgts[BMo];

    int e  = blockIdx.x >> 3;
    int n0 = (blockIdx.x & 7) * BNo;
    int cnt = counts[e];
    if (cnt > cap) cnt = cap;
    if (cnt == 0) return;
    int ntiles = (cnt + BMo - 1) / BMo;

    int tid  = threadIdx.x;
    int lane = tid & 63;
    int wv = tid >> 6;
    int wm = wv >> 1;
    int wn = wv & 1;

    int arow = tid >> 1;
    int acol = (tid & 1) * 32;
    int brow = tid >> 2;
    int bcol = (tid & 3) * 16;
    const float* wbasef = ew + ((size_t)e << 20) + (size_t)(n0 + brow) * DIM + bcol;
    const short* wbaseb = wb + ((size_t)e << 20) + (size_t)(n0 + brow) * DIM + bcol;

    float4 raf[8];
    uint4  rab[4];
    float4 rbf[4];
    uint4  rbb[2];

    for (int mtt = 0; mtt < ntiles; ++mtt) {
        __syncthreads();
        if (tid < BMo) {
            size_t base = (size_t)e * cap + (size_t)mtt * BMo + tid;
            slots[tid] = tlist[base];
            wgts[tid]  = wlist[base];
        }
        __syncthreads();

        floatx4 acc[4][4];
        #pragma unroll
        for (int i = 0; i < 4; ++i)
            #pragma unroll
            for (int j = 0; j < 4; ++j) acc[i][j] = (floatx4)0.0f;

        size_t trow = (size_t)(slots[arow] >> 3);
        const float* hrowf = h  + trow * DIM + acol;
        const short* hrowb = hb + trow * DIM + acol;

        if constexpr (AB) {
            #pragma unroll
            for (int j = 0; j < 4; ++j) rab[j] = *(const uint4*)(hrowb + j*8);
        } else {
            #pragma unroll
            for (int j = 0; j < 4; ++j) {
                raf[2*j]   = *(const float4*)(hrowf + j*8);
                raf[2*j+1] = *(const float4*)(hrowf + j*8 + 4);
            }
        }
        if constexpr (WB) {
            #pragma unroll
            for (int j = 0; j < 2; ++j) rbb[j] = *(const uint4*)(wbaseb + j*8);
        } else {
            #pragma unroll
            for (int j = 0; j < 4; ++j) rbf[j] = *(const float4*)(wbasef + j*4);
        }

        for (int k0 = 0; k0 < DIM; k0 += 64) {
            if constexpr (AB) {
                #pragma unroll
                for (int j = 0; j < 4; ++j)
                    *(uint4*)&As[arow*LDT + acol + j*8] = rab[j];
            } else {
                #pragma unroll
                for (int j = 0; j < 4; ++j)
                    *(short8*)&As[arow*LDT + acol + j*8] = pack8(raf[2*j], raf[2*j+1]);
            }
            if constexpr (WB) {
                #pragma unroll
                for (int j = 0; j < 2; ++j)
                    *(uint4*)&Bs[brow*LDT + bcol + j*8] = rbb[j];
            } else {
                #pragma unroll
                for (int j = 0; j < 2; ++j)
                    *(short8*)&Bs[brow*LDT + bcol + j*8] = pack8(rbf[2*j], rbf[2*j+1]);
            }
            __syncthreads();

            int kn = k0 + 64;
            if (kn < DIM) {
                if constexpr (AB) {
                    #pragma unroll
                    for (int j = 0; j < 4; ++j) rab[j] = *(const uint4*)(hrowb + kn + j*8);
                } else {
                    #pragma unroll
                    for (int j = 0; j < 4; ++j) {
                        raf[2*j]   = *(const float4*)(hrowf + kn + j*8);
                        raf[2*j+1] = *(const float4*)(hrowf + kn + j*8 + 4);
                    }
                }
                if constexpr (WB) {
                    #pragma unroll
                    for (int j = 0; j < 2; ++j) rbb[j] = *(const uint4*)(wbaseb + kn + j*8);
                } else {
                    #pragma unroll
                    for (int j = 0; j < 4; ++j) rbf[j] = *(const float4*)(wbasef + kn + j*4);
                }
            }

            #pragma unroll
            for (int s = 0; s < 2; ++s) {
                int ko = s*32 + (lane >> 4) * 8;
                int rr = lane & 15;
                short8 af[4], bfr[4];
                #pragma unroll
                for (int mm = 0; mm < 4; ++mm)
                    af[mm] = *(const short8*)&As[(wm*64 + mm*16 + rr)*LDT + ko];
                #pragma unroll
                for (int nn = 0; nn < 4; ++nn)
                    bfr[nn] = *(const short8*)&Bs[(wn*64 + nn*16 + rr)*LDT + ko];
                #pragma unroll
                for (int mm = 0; mm < 4; ++mm)
                    #pragma unroll
                    for (int nn = 0; nn < 4; ++nn)
                        acc[mm][nn] = __builtin_amdgcn_mfma_f32_16x16x32_bf16(
                            af[mm], bfr[nn], acc[mm][nn], 0, 0, 0);
            }
            __syncthreads();
        }

        int cgrp = lane >> 4;
        int ccol = lane & 15;
        #pragma unroll
        for (int mm = 0; mm < 4; ++mm) {
            #pragma unroll
            for (int r = 0; r < 4; ++r) {
                int row = wm*64 + mm*16 + cgrp*4 + r;
                float wgt = wgts[row];
                if (wgt != 0.0f) {
                    size_t tok = (size_t)(slots[row] >> 3);
                    #pragma unroll
                    for (int nn = 0; nn < 4; ++nn) {
                        int col = n0 + wn*64 + nn*16 + ccol;
                        atomicAdd(&out[tok * DIM + col], wgt * acc[mm][nn][r]);
                    }
                }
            }
        }
    }
}

// ---------------- gather: out[t] = sum_k contrib[t*8+k] ----------------
__global__ void k_gather(const unsigned short* __restrict__ contrib,
                         float* __restrict__ out) {
    int t = blockIdx.x;
    int c = threadIdx.x * 4;
    float4 s = {0.f, 0.f, 0.f, 0.f};
    #pragma unroll
    for (int k = 0; k < TOPK; ++k) {
        ushort4v v = *(const ushort4v*)(contrib + ((size_t)t * TOPK + k) * DIM + c);
        s.x += bf2f(v[0]); s.y += bf2f(v[1]); s.z += bf2f(v[2]); s.w += bf2f(v[3]);
    }
    *(float4*)(out + (size_t)t * DIM + c) = s;
}

extern "C" void kernel_launch(void* const* d_in, const int* in_sizes, int n_in,
                              void* d_out, int out_size, void* d_ws, size_t ws_size,
                              hipStream_t stream) {
    const float* h  = (const float*)d_in[0];
    const float* gw = (const float*)d_in[1];
    const float* ew = (const float*)d_in[2];
    float* out    = (float*)d_out;
    float* logits = out + (size_t)N_TOK * DIM;

    const size_t SZ_TK   = (size_t)N_TOK * TOPK * 4;
    const size_t SZ_HB   = (size_t)N_TOK * DIM * 2;
    const size_t SZ_WB   = (size_t)NEXP * DIM * DIM * 2;
    const size_t SZ_CT   = (size_t)N_TOK * TOPK * DIM * 2;
    const size_t SZ_LIST = (size_t)CAPF * NEXP * 4;

    size_t need_base = 4096 + 2*SZ_LIST + 2*SZ_TK + SZ_HB;
    size_t need_t1   = need_base + SZ_WB;
    size_t need_t2   = need_t1 + SZ_CT;

    int tier;
    long cap = CAPF;
    if      (ws_size >= need_t2)   tier = 3;
    else if (ws_size >= need_t1)   tier = 2;
    else if (ws_size >= need_base) tier = 1;
    else {
        tier = 0;
        size_t avail = (ws_size > 4096 + 2*SZ_TK) ? ws_size - 4096 - 2*SZ_TK : 0;
        cap = (long)(avail / ((size_t)NEXP * 8));
        cap &= ~255L;
        if (cap > N_TOK) cap = N_TOK;
    }

    char* ws = (char*)d_ws;
    size_t off = 0;
    int*   counts = (int*)(ws + off);  off += 4096;
    int*   tlist  = (int*)(ws + off);  off += (size_t)cap * NEXP * 4;
    float* wlist  = (float*)(ws + off); off += (size_t)cap * NEXP * 4;
    int*   tki    = (int*)(ws + off);  off += SZ_TK;
    float* tkw    = (float*)(ws + off); off += SZ_TK;
    short* hb     = (short*)(ws + off); if (tier >= 1) off += SZ_HB;
    short* wbuf   = (short*)(ws + off); if (tier >= 2) off += SZ_WB;
    unsigned short* contrib = (unsigned short*)(ws + off);

    k_router<<<dim3(N_TOK/32), 256, 0, stream>>>(h, gw, logits);

    if (cap < 256) return;

    hipMemsetAsync(counts, 0, 256, stream);
    hipMemsetAsync(tlist, 0, (size_t)cap*NEXP*4, stream);
    hipMemsetAsync(wlist, 0, (size_t)cap*NEXP*4, stream);
    if (tier < 3) hipMemsetAsync(out, 0, (size_t)N_TOK*DIM*4, stream);

    if (tier >= 1)
        k_convert<<<dim3((N_TOK*DIM)/(256*8)), 256, 0, stream>>>(h, hb);
    if (tier >= 2)
        k_convert<<<dim3((unsigned)((size_t)NEXP*DIM*DIM/(256*8))), 256, 0, stream>>>(ew, wbuf);

    k_topk1<<<dim3(N_TOK/4), 256, 0, stream>>>(logits, tki, tkw);
    k_topk2<<<dim3(NEXP), 256, 0, stream>>>(tki, tkw, counts, tlist, wlist, (int)cap);

    if (tier == 3) {
        k_moe3<<<dim3(16 * 512), 256, 0, stream>>>(
            hb, wbuf, counts, tlist, wlist, contrib, (int)cap);
        k_gather<<<dim3(N_TOK), 256, 0, stream>>>(contrib, out);
    } else if (tier == 2) {
        k_moe<true,true><<<dim3(NEXP*8), 512, 0, stream>>>(
            h, hb, ew, wbuf, counts, tlist, wlist, out, (int)cap);
    } else if (tier == 1) {
        k_moe<true,false><<<dim3(NEXP*8), 512, 0, stream>>>(
            h, hb, ew, wbuf, counts, tlist, wlist, out, (int)cap);
    } else {
        k_moe<false,false><<<dim3(NEXP*8), 512, 0, stream>>>(
            h, hb, ew, wbuf, counts, tlist, wlist, out, (int)cap);
    }
}

// Round 8
// 515.475 us; speedup vs baseline: 5.4739x; 1.0126x over previous
//
#include <hip/hip_runtime.h>
#include <hip/hip_bf16.h>
#include <math.h>

#define N_TOK 8192
#define DIM   1024
#define NEXP  64
#define TOPK  8
#define CAPF  2048     // per-expert list capacity (mean 1024, ~34 sigma headroom)

typedef __attribute__((ext_vector_type(8))) short short8;
typedef __attribute__((ext_vector_type(4))) float floatx4;
typedef __attribute__((ext_vector_type(4))) unsigned short ushort4v;
typedef unsigned int u32;

static __device__ __forceinline__ short f2bf(float f) {
    union { float f; unsigned u; } c; c.f = f;
    unsigned r = c.u + 0x7FFF + ((c.u >> 16) & 1);   // RNE
    return (short)(r >> 16);
}
static __device__ __forceinline__ float bf2f(unsigned short s) {
    union { unsigned u; float f; } c; c.u = ((unsigned)s) << 16;
    return c.f;
}
static __device__ __forceinline__ short8 pack8(float4 a, float4 b) {
    short8 o;
    o[0]=f2bf(a.x); o[1]=f2bf(a.y); o[2]=f2bf(a.z); o[3]=f2bf(a.w);
    o[4]=f2bf(b.x); o[5]=f2bf(b.y); o[6]=f2bf(b.z); o[7]=f2bf(b.w);
    return o;
}
// async global->LDS, 16B per lane; lds ptr wave-uniform (HW: base + lane*16)
static __device__ __forceinline__ void gll16(const short* g, short* l) {
    __builtin_amdgcn_global_load_lds(
        (const __attribute__((address_space(1))) u32*)(const void*)g,
        (__attribute__((address_space(3))) u32*)(void*)l, 16, 0, 0);
}

// ---------------- fp32 -> bf16 bulk convert ----------------
__global__ void k_convert(const float* __restrict__ src, short* __restrict__ dst) {
    size_t i = ((size_t)blockIdx.x * 256 + threadIdx.x) * 8;
    float4 f0 = *(const float4*)(src + i);
    float4 f1 = *(const float4*)(src + i + 4);
    *(short8*)(dst + i) = pack8(f0, f1);
}

// ---------------- router logits (fp32, known-correct) ----------------
__global__ void k_router(const float* __restrict__ h, const float* __restrict__ gw,
                         float* __restrict__ logits) {
    __shared__ float hs[32 * 68];
    __shared__ float gs[64 * 68];
    int tid = threadIdx.x;
    int t0 = blockIdx.x * 32;
    int tm = tid & 15;
    int en = tid >> 4;
    float acc[2][4] = {{0.f,0.f,0.f,0.f},{0.f,0.f,0.f,0.f}};

    for (int k0 = 0; k0 < DIM; k0 += 64) {
        {
            int row = tid >> 3, seg = (tid & 7) * 8;
            const float* src = h + (size_t)(t0 + row) * DIM + k0 + seg;
            *(float4*)&hs[row*68 + seg]     = *(const float4*)src;
            *(float4*)&hs[row*68 + seg + 4] = *(const float4*)(src + 4);
        }
        {
            int row = tid >> 2, seg = (tid & 3) * 16;
            const float* src = gw + (size_t)row * DIM + k0 + seg;
            float4* dst = (float4*)&gs[row*68 + seg];
            #pragma unroll
            for (int j = 0; j < 4; ++j) dst[j] = *(const float4*)(src + j*4);
        }
        __syncthreads();
        #pragma unroll
        for (int k4 = 0; k4 < 16; ++k4) {
            float4 h0 = *(const float4*)&hs[tm*68 + k4*4];
            float4 h1 = *(const float4*)&hs[(tm+16)*68 + k4*4];
            #pragma unroll
            for (int j = 0; j < 4; ++j) {
                float4 g = *(const float4*)&gs[(en + 16*j)*68 + k4*4];
                acc[0][j] += h0.x*g.x + h0.y*g.y + h0.z*g.z + h0.w*g.w;
                acc[1][j] += h1.x*g.x + h1.y*g.y + h1.z*g.z + h1.w*g.w;
            }
        }
        __syncthreads();
    }
    #pragma unroll
    for (int r = 0; r < 2; ++r)
        #pragma unroll
        for (int j = 0; j < 4; ++j)
            logits[(size_t)(t0 + tm + 16*r) * NEXP + en + 16*j] = acc[r][j];
}

// ---------------- phase 1: per-token softmax + top-8 ----------------
__global__ void k_topk1(const float* __restrict__ logits,
                        int* __restrict__ tki, float* __restrict__ tkw) {
    int t = blockIdx.x * 4 + (threadIdx.x >> 6);
    int lane = threadIdx.x & 63;
    float x = logits[(size_t)t * NEXP + lane];

    float m = x;
    #pragma unroll
    for (int off = 32; off; off >>= 1) m = fmaxf(m, __shfl_xor(m, off));
    float p = expf(x - m);
    float s = p;
    #pragma unroll
    for (int off = 32; off; off >>= 1) s += __shfl_xor(s, off);
    float w = p / s;

    float cur = w;
    for (int k = 0; k < TOPK; ++k) {
        float v = cur; int idx = lane;
        #pragma unroll
        for (int off = 32; off; off >>= 1) {
            float ov = __shfl_xor(v, off);
            int   oi = __shfl_xor(idx, off);
            if (ov > v || (ov == v && oi < idx)) { v = ov; idx = oi; }
        }
        if (lane == idx) cur = -1.0f;
        if (lane == 0) {
            tki[(size_t)t * TOPK + k] = idx;
            tkw[(size_t)t * TOPK + k] = v;
        }
    }
}

// ---------------- phase 2: compaction into token-sorted per-expert lists ----------------
__global__ void k_topk2(const int* __restrict__ tki, const float* __restrict__ tkw,
                        int* __restrict__ counts, int* __restrict__ tlist,
                        float* __restrict__ wlist, int cap) {
    int e = blockIdx.x, tid = threadIdx.x, lane = tid & 63, wv = tid >> 6;
    __shared__ int wtot[4];
    __shared__ int carry_s;
    if (tid == 0) carry_s = 0;
    __syncthreads();

    for (int c0 = 0; c0 < N_TOK * TOPK; c0 += 1024) {
        int i = c0 + tid * 4;
        int4 v = *(const int4*)(tki + i);
        int m0 = (v.x == e), m1 = (v.y == e), m2 = (v.z == e), m3 = (v.w == e);
        int mc = m0 + m1 + m2 + m3;
        int sc = mc;
        #pragma unroll
        for (int off = 1; off < 64; off <<= 1) {
            int o = __shfl_up(sc, off);
            if (lane >= off) sc += o;
        }
        if (lane == 63) wtot[wv] = sc;
        int excl = sc - mc;
        __syncthreads();
        int wbase = 0;
        #pragma unroll
        for (int j = 0; j < 4; ++j) if (j < wv) wbase += wtot[j];
        int tot = wtot[0] + wtot[1] + wtot[2] + wtot[3];
        int pos = carry_s + wbase + excl;
        if (m0) { if (pos < cap) { tlist[(size_t)e*cap+pos] = i;   wlist[(size_t)e*cap+pos] = tkw[i];   } pos++; }
        if (m1) { if (pos < cap) { tlist[(size_t)e*cap+pos] = i+1; wlist[(size_t)e*cap+pos] = tkw[i+1]; } pos++; }
        if (m2) { if (pos < cap) { tlist[(size_t)e*cap+pos] = i+2; wlist[(size_t)e*cap+pos] = tkw[i+2]; } pos++; }
        if (m3) { if (pos < cap) { tlist[(size_t)e*cap+pos] = i+3; wlist[(size_t)e*cap+pos] = tkw[i+3]; } pos++; }
        __syncthreads();
        if (tid == 0) carry_s += tot;
        __syncthreads();
    }
    if (tid == 0) counts[e] = min(carry_s, cap);
}

// ================= tier-3: 128x128 tile, double-buffered global_load_lds =================
// grid: bx = (g/8)*128 + mt*8 + (g%8) where g = e*8+nt. bx%8 = g%8 pins all 16
// m-tile sharers of a W slice to one XCD in CONSECUTIVE queue slots (L2-hot W).
#define PADW 136
__global__ __launch_bounds__(256) void k_moe3(
    const short* __restrict__ hb, const short* __restrict__ wb,
    const int* __restrict__ counts, const int* __restrict__ tlist,
    const float* __restrict__ wlist, unsigned short* __restrict__ contrib, int cap)
{
    __shared__ short As[2][128 * 64];   // linear, chunk-swizzled: pos(row,c) holds chunk c^(row&7)
    __shared__ short Bs[2][128 * 64];
    __shared__ int   slots[128];
    __shared__ float wgts[128];

    int bx = blockIdx.x;
    int g  = ((bx >> 7) << 3) | (bx & 7);   // 0..511
    int mt = (bx >> 3) & 15;
    int e  = g >> 3;
    int n0 = (g & 7) * 128;
    int cnt = counts[e]; if (cnt > cap) cnt = cap;
    if (mt * 128 >= cnt) return;

    int tid = threadIdx.x, lane = tid & 63, w = tid >> 6;
    int wm = w >> 1, wn = w & 1;

    if (tid < 128) {
        size_t base = (size_t)e * cap + (size_t)mt * 128 + tid;
        slots[tid] = tlist[base];
        wgts[tid]  = wlist[base];
    }
    __syncthreads();

    // per-lane global source addresses (pre-swizzled chunk)
    const short* aaddr[4];
    const short* baddr[4];
    #pragma unroll
    for (int i = 0; i < 4; ++i) {
        int row = (w*4 + i)*8 + (lane >> 3);
        int gch = (lane & 7) ^ (row & 7);
        int tok = slots[row] >> 3;
        aaddr[i] = hb + (size_t)tok * DIM + gch*8;
        baddr[i] = wb + ((size_t)e << 20) + (size_t)(n0 + row) * DIM + gch*8;
    }

    floatx4 acc[4][4];
    #pragma unroll
    for (int i = 0; i < 4; ++i)
        #pragma unroll
        for (int j = 0; j < 4; ++j) acc[i][j] = (floatx4)0.0f;

    // prologue: stage tile 0 into buf 0
    #pragma unroll
    for (int i = 0; i < 4; ++i) {
        gll16(aaddr[i], &As[0][(w*4 + i)*512]);
        gll16(baddr[i], &Bs[0][(w*4 + i)*512]);
    }

    #pragma unroll
    for (int ks = 0; ks < 16; ++ks) {
        const int cur = ks & 1;
        // issue next tile's loads into the other buffer (its readers finished
        // at the trailing barrier of iteration ks-1)
        if (ks < 15) {
            #pragma unroll
            for (int i = 0; i < 4; ++i) {
                gll16(aaddr[i] + (ks+1)*64, &As[cur^1][(w*4 + i)*512]);
                gll16(baddr[i] + (ks+1)*64, &Bs[cur^1][(w*4 + i)*512]);
            }
            asm volatile("s_waitcnt vmcnt(8)" ::: "memory");   // tile ks resident
        } else {
            asm volatile("s_waitcnt vmcnt(0)" ::: "memory");
        }
        __builtin_amdgcn_s_barrier();      // all waves' tile-ks loads visible

        #pragma unroll
        for (int s = 0; s < 2; ++s) {
            int gch = s*4 + (lane >> 4);
            int rr  = lane & 15;
            short8 af[4], bfr[4];
            #pragma unroll
            for (int mm = 0; mm < 4; ++mm) {
                int row = wm*64 + mm*16 + rr;
                af[mm] = *(const short8*)&As[cur][row*64 + ((gch ^ (row & 7)) * 8)];
            }
            #pragma unroll
            for (int nn = 0; nn < 4; ++nn) {
                int row = wn*64 + nn*16 + rr;
                bfr[nn] = *(const short8*)&Bs[cur][row*64 + ((gch ^ (row & 7)) * 8)];
            }
            #pragma unroll
            for (int mm = 0; mm < 4; ++mm)
                #pragma unroll
                for (int nn = 0; nn < 4; ++nn)
                    acc[mm][nn] = __builtin_amdgcn_mfma_f32_16x16x32_bf16(
                        af[mm], bfr[nn], acc[mm][nn], 0, 0, 0);
        }
        __builtin_amdgcn_s_barrier();      // reads of buf cur done before overwrite
    }

    // epilogue: LDS transpose (reuse As[0]) -> 32B-contiguous bf16 stores
    short* pad = As[0];    // 32*PADW = 4352 shorts <= 8192
    int cgrp = lane >> 4, ccol = lane & 15;
    #pragma unroll
    for (int mm = 0; mm < 4; ++mm) {
        __syncthreads();
        #pragma unroll
        for (int r = 0; r < 4; ++r) {
            int sub = cgrp*4 + r;
            float wgt = wgts[wm*64 + mm*16 + sub];
            #pragma unroll
            for (int nn = 0; nn < 4; ++nn)
                pad[(wm*16 + sub)*PADW + wn*64 + nn*16 + ccol] =
                    f2bf(wgt * acc[mm][nn][r]);
        }
        __syncthreads();
        int rr = tid >> 3, ch = tid & 7;
        int wm2 = rr >> 4, sub = rr & 15;
        int grow = wm2*64 + mm*16 + sub;
        if (wgts[grow] != 0.0f) {
            size_t base = (size_t)slots[grow] * DIM + n0 + ch*16;
            uint4 v0 = *(const uint4*)&pad[rr*PADW + ch*16];
            uint4 v1 = *(const uint4*)&pad[rr*PADW + ch*16 + 8];
            *(uint4*)&contrib[base]     = v0;
            *(uint4*)&contrib[base + 8] = v1;
        }
    }
}

// ---------------- fallback gathered GEMM (tiers 0-2, atomics) ----------------
#define BMo 256
#define BNo 128
#define LDT 72
template<bool AB, bool WB>
__global__ __launch_bounds__(512) void k_moe(
    const float* __restrict__ h, const short* __restrict__ hb,
    const float* __restrict__ ew, const short* __restrict__ wb,
    const int* __restrict__ counts, const int* __restrict__ tlist,
    const float* __restrict__ wlist, float* __restrict__ out, int cap)
{
    __shared__ short As[BMo * LDT];
    __shared__ short Bs[BNo * LDT];
    __shared__ int   slots[BMo];
    __shared__ float wgts[BMo];

    int e  = blockIdx.x >> 3;
    int n0 = (blockIdx.x & 7) * BNo;
    int cnt = counts[e];
    if (cnt > cap) cnt = cap;
    if (cnt == 0) return;
    int ntiles = (cnt + BMo - 1) / BMo;

    int tid  = threadIdx.x;
    int lane = tid & 63;
    int wv = tid >> 6;
    int wm = wv >> 1;
    int wn = wv & 1;

    int arow = tid >> 1;
    int acol = (tid & 1) * 32;
    int brow = tid >> 2;
    int bcol = (tid & 3) * 16;
    const float* wbasef = ew + ((size_t)e << 20) + (size_t)(n0 + brow) * DIM + bcol;
    const short* wbaseb = wb + ((size_t)e << 20) + (size_t)(n0 + brow) * DIM + bcol;

    float4 raf[8];
    uint4  rab[4];
    float4 rbf[4];
    uint4  rbb[2];

    for (int mtt = 0; mtt < ntiles; ++mtt) {
        __syncthreads();
        if (tid < BMo) {
            size_t base = (size_t)e * cap + (size_t)mtt * BMo + tid;
            slots[tid] = tlist[base];
            wgts[tid]  = wlist[base];
        }
        __syncthreads();

        floatx4 acc[4][4];
        #pragma unroll
        for (int i = 0; i < 4; ++i)
            #pragma unroll
            for (int j = 0; j < 4; ++j) acc[i][j] = (floatx4)0.0f;

        size_t trow = (size_t)(slots[arow] >> 3);
        const float* hrowf = h  + trow * DIM + acol;
        const short* hrowb = hb + trow * DIM + acol;

        if constexpr (AB) {
            #pragma unroll
            for (int j = 0; j < 4; ++j) rab[j] = *(const uint4*)(hrowb + j*8);
        } else {
            #pragma unroll
            for (int j = 0; j < 4; ++j) {
                raf[2*j]   = *(const float4*)(hrowf + j*8);
                raf[2*j+1] = *(const float4*)(hrowf + j*8 + 4);
            }
        }
        if constexpr (WB) {
            #pragma unroll
            for (int j = 0; j < 2; ++j) rbb[j] = *(const uint4*)(wbaseb + j*8);
        } else {
            #pragma unroll
            for (int j = 0; j < 4; ++j) rbf[j] = *(const float4*)(wbasef + j*4);
        }

        for (int k0 = 0; k0 < DIM; k0 += 64) {
            if constexpr (AB) {
                #pragma unroll
                for (int j = 0; j < 4; ++j)
                    *(uint4*)&As[arow*LDT + acol + j*8] = rab[j];
            } else {
                #pragma unroll
                for (int j = 0; j < 4; ++j)
                    *(short8*)&As[arow*LDT + acol + j*8] = pack8(raf[2*j], raf[2*j+1]);
            }
            if constexpr (WB) {
                #pragma unroll
                for (int j = 0; j < 2; ++j)
                    *(uint4*)&Bs[brow*LDT + bcol + j*8] = rbb[j];
            } else {
                #pragma unroll
                for (int j = 0; j < 2; ++j)
                    *(short8*)&Bs[brow*LDT + bcol + j*8] = pack8(rbf[2*j], rbf[2*j+1]);
            }
            __syncthreads();

            int kn = k0 + 64;
            if (kn < DIM) {
                if constexpr (AB) {
                    #pragma unroll
                    for (int j = 0; j < 4; ++j) rab[j] = *(const uint4*)(hrowb + kn + j*8);
                } else {
                    #pragma unroll
                    for (int j = 0; j < 4; ++j) {
                        raf[2*j]   = *(const float4*)(hrowf + kn + j*8);
                        raf[2*j+1] = *(const float4*)(hrowf + kn + j*8 + 4);
                    }
                }
                if constexpr (WB) {
                    #pragma unroll
                    for (int j = 0; j < 2; ++j) rbb[j] = *(const uint4*)(wbaseb + kn + j*8);
                } else {
                    #pragma unroll
                    for (int j = 0; j < 4; ++j) rbf[j] = *(const float4*)(wbasef + kn + j*4);
                }
            }

            #pragma unroll
            for (int s = 0; s < 2; ++s) {
                int ko = s*32 + (lane >> 4) * 8;
                int rr = lane & 15;
                short8 af[4], bfr[4];
                #pragma unroll
                for (int mm = 0; mm < 4; ++mm)
                    af[mm] = *(const short8*)&As[(wm*64 + mm*16 + rr)*LDT + ko];
                #pragma unroll
                for (int nn = 0; nn < 4; ++nn)
                    bfr[nn] = *(const short8*)&Bs[(wn*64 + nn*16 + rr)*LDT + ko];
                #pragma unroll
                for (int mm = 0; mm < 4; ++mm)
                    #pragma unroll
                    for (int nn = 0; nn < 4; ++nn)
                        acc[mm][nn] = __builtin_amdgcn_mfma_f32_16x16x32_bf16(
                            af[mm], bfr[nn], acc[mm][nn], 0, 0, 0);
            }
            __syncthreads();
        }

        int cgrp = lane >> 4;
        int ccol = lane & 15;
        #pragma unroll
        for (int mm = 0; mm < 4; ++mm) {
            #pragma unroll
            for (int r = 0; r < 4; ++r) {
                int row = wm*64 + mm*16 + cgrp*4 + r;
                float wgt = wgts[row];
                if (wgt != 0.0f) {
                    size_t tok = (size_t)(slots[row] >> 3);
                    #pragma unroll
                    for (int nn = 0; nn < 4; ++nn) {
                        int col = n0 + wn*64 + nn*16 + ccol;
                        atomicAdd(&out[tok * DIM + col], wgt * acc[mm][nn][r]);
                    }
                }
            }
        }
    }
}

// ---------------- gather: out[t] = sum_k contrib[t*8+k] ----------------
__global__ void k_gather(const unsigned short* __restrict__ contrib,
                         float* __restrict__ out) {
    int t = blockIdx.x;
    int c = threadIdx.x * 4;
    float4 s = {0.f, 0.f, 0.f, 0.f};
    #pragma unroll
    for (int k = 0; k < TOPK; ++k) {
        ushort4v v = *(const ushort4v*)(contrib + ((size_t)t * TOPK + k) * DIM + c);
        s.x += bf2f(v[0]); s.y += bf2f(v[1]); s.z += bf2f(v[2]); s.w += bf2f(v[3]);
    }
    *(float4*)(out + (size_t)t * DIM + c) = s;
}

extern "C" void kernel_launch(void* const* d_in, const int* in_sizes, int n_in,
                              void* d_out, int out_size, void* d_ws, size_t ws_size,
                              hipStream_t stream) {
    const float* h  = (const float*)d_in[0];
    const float* gw = (const float*)d_in[1];
    const float* ew = (const float*)d_in[2];
    float* out    = (float*)d_out;
    float* logits = out + (size_t)N_TOK * DIM;

    const size_t SZ_TK   = (size_t)N_TOK * TOPK * 4;
    const size_t SZ_HB   = (size_t)N_TOK * DIM * 2;
    const size_t SZ_WB   = (size_t)NEXP * DIM * DIM * 2;
    const size_t SZ_CT   = (size_t)N_TOK * TOPK * DIM * 2;
    const size_t SZ_LIST = (size_t)CAPF * NEXP * 4;

    size_t need_base = 4096 + 2*SZ_LIST + 2*SZ_TK + SZ_HB;
    size_t need_t1   = need_base + SZ_WB;
    size_t need_t2   = need_t1 + SZ_CT;

    int tier;
    long cap = CAPF;
    if      (ws_size >= need_t2)   tier = 3;
    else if (ws_size >= need_t1)   tier = 2;
    else if (ws_size >= need_base) tier = 1;
    else {
        tier = 0;
        size_t avail = (ws_size > 4096 + 2*SZ_TK) ? ws_size - 4096 - 2*SZ_TK : 0;
        cap = (long)(avail / ((size_t)NEXP * 8));
        cap &= ~255L;
        if (cap > N_TOK) cap = N_TOK;
    }

    char* ws = (char*)d_ws;
    size_t off = 0;
    int*   counts = (int*)(ws + off);  off += 4096;
    int*   tlist  = (int*)(ws + off);  off += (size_t)cap * NEXP * 4;
    float* wlist  = (float*)(ws + off); off += (size_t)cap * NEXP * 4;
    int*   tki    = (int*)(ws + off);  off += SZ_TK;
    float* tkw    = (float*)(ws + off); off += SZ_TK;
    short* hb     = (short*)(ws + off); if (tier >= 1) off += SZ_HB;
    short* wbuf   = (short*)(ws + off); if (tier >= 2) off += SZ_WB;
    unsigned short* contrib = (unsigned short*)(ws + off);

    k_router<<<dim3(N_TOK/32), 256, 0, stream>>>(h, gw, logits);

    if (cap < 256) return;

    hipMemsetAsync(counts, 0, 256, stream);
    hipMemsetAsync(tlist, 0, (size_t)cap*NEXP*4, stream);
    hipMemsetAsync(wlist, 0, (size_t)cap*NEXP*4, stream);
    if (tier < 3) hipMemsetAsync(out, 0, (size_t)N_TOK*DIM*4, stream);

    if (tier >= 1)
        k_convert<<<dim3((N_TOK*DIM)/(256*8)), 256, 0, stream>>>(h, hb);
    if (tier >= 2)
        k_convert<<<dim3((unsigned)((size_t)NEXP*DIM*DIM/(256*8))), 256, 0, stream>>>(ew, wbuf);

    k_topk1<<<dim3(N_TOK/4), 256, 0, stream>>>(logits, tki, tkw);
    k_topk2<<<dim3(NEXP), 256, 0, stream>>>(tki, tkw, counts, tlist, wlist, (int)cap);

    if (tier == 3) {
        k_moe3<<<dim3(16 * 512), 256, 0, stream>>>(
            hb, wbuf, counts, tlist, wlist, contrib, (int)cap);
        k_gather<<<dim3(N_TOK), 256, 0, stream>>>(contrib, out);
    } else if (tier == 2) {
        k_moe<true,true><<<dim3(NEXP*8), 512, 0, stream>>>(
            h, hb, ew, wbuf, counts, tlist, wlist, out, (int)cap);
    } else if (tier == 1) {
        k_moe<true,false><<<dim3(NEXP*8), 512, 0, stream>>>(
            h, hb, ew, wbuf, counts, tlist, wlist, out, (int)cap);
    } else {
        k_moe<false,false><<<dim3(NEXP*8), 512, 0, stream>>>(
            h, hb, ew, wbuf, counts, tlist, wlist, out, (int)cap);
    }
}